// Round 1
// baseline (135.622 us; speedup 1.0000x reference)
//
#include <hip/hip_runtime.h>
#include <hip/hip_bf16.h>
#include <stdint.h>

#define N_PTS 4096
#define DIM 512
#define MARGIN_F 0.3f
#define POS_INF_BITS 0x7f800000

typedef short bf16x8 __attribute__((ext_vector_type(8)));
typedef float f32x4 __attribute__((ext_vector_type(4)));

__device__ __forceinline__ unsigned short f2bf(float f) {
    unsigned int b = __float_as_uint(f);
    b += 0x7FFF + ((b >> 16) & 1);   // round-to-nearest-even
    return (unsigned short)(b >> 16);
}

// One block per row: bf16 copies + exact fp32 norms + init ap/an.
__global__ __launch_bounds__(128) void prep_kernel(
    const float* __restrict__ src, const float* __restrict__ tgt,
    unsigned short* __restrict__ src_bf, unsigned short* __restrict__ tgt_bf,
    float* __restrict__ e1, float* __restrict__ e2,
    float* __restrict__ ap, float* __restrict__ an)
{
    const int row = blockIdx.x;
    const int t = threadIdx.x;   // 128 threads, 4 floats each = 512

    float4 a = ((const float4*)(src + (size_t)row * DIM))[t];
    float4 b = ((const float4*)(tgt + (size_t)row * DIM))[t];

    ushort4 abf, bbf;
    abf.x = f2bf(a.x); abf.y = f2bf(a.y); abf.z = f2bf(a.z); abf.w = f2bf(a.w);
    bbf.x = f2bf(b.x); bbf.y = f2bf(b.y); bbf.z = f2bf(b.z); bbf.w = f2bf(b.w);
    ((ushort4*)(src_bf + (size_t)row * DIM))[t] = abf;
    ((ushort4*)(tgt_bf + (size_t)row * DIM))[t] = bbf;

    float s1 = a.x*a.x + a.y*a.y + a.z*a.z + a.w*a.w;
    float s2 = b.x*b.x + b.y*b.y + b.z*b.z + b.w*b.w;
    for (int off = 32; off; off >>= 1) {
        s1 += __shfl_down(s1, off);
        s2 += __shfl_down(s2, off);
    }
    __shared__ float red[4];
    if ((t & 63) == 0) { red[t >> 6] = s1; red[2 + (t >> 6)] = s2; }
    __syncthreads();
    if (t == 0) {
        e1[row] = red[0] + red[1];
        e2[row] = red[2] + red[3];
        ap[row] = 0.0f;
        an[row] = __int_as_float(POS_INF_BITS);
    }
}

#define BM 64
#define BN 64
#define BK 32
#define LDS_K (BK + 8)   // +8 bf16 pad: row stride 80B = 20 words -> 2-way max (free)

__global__ __launch_bounds__(256) void dist_kernel(
    const unsigned short* __restrict__ src_bf,
    const unsigned short* __restrict__ tgt_bf,
    const float* __restrict__ e1, const float* __restrict__ e2,
    const int* __restrict__ labels,
    float* __restrict__ ap, float* __restrict__ an)
{
    __shared__ unsigned short As[BM][LDS_K];
    __shared__ unsigned short Bs[BN][LDS_K];
    __shared__ int li[BM];
    __shared__ int lj[BN];
    __shared__ float e1s[BM];
    __shared__ float e2s[BN];

    const int i0 = blockIdx.y * BM;
    const int j0 = blockIdx.x * BN;
    const int t = threadIdx.x;
    const int lane = t & 63;
    const int wave = t >> 6;

    if (t < BM)               { li[t] = labels[i0 + t];      e1s[t] = e1[i0 + t]; }
    else if (t < BM + BN)     { int u = t - BM; lj[u] = labels[j0 + u]; e2s[u] = e2[j0 + u]; }

    // staging map: 256 threads, 16B each per tile
    const int srow = t >> 2;          // 0..63
    const int sseg = (t & 3) * 8;     // bf16 offset 0,8,16,24

    // wave -> 32x32 subtile
    const int wm = (wave >> 1) * 32;
    const int wn = (wave & 1) * 32;
    const int fr = lane & 15;
    const int quad = lane >> 4;
    const int fk = quad * 8;

    f32x4 acc[2][2];
    #pragma unroll
    for (int a = 0; a < 2; a++)
        #pragma unroll
        for (int b = 0; b < 2; b++)
            acc[a][b] = (f32x4){0.f, 0.f, 0.f, 0.f};

    for (int kk = 0; kk < DIM; kk += BK) {
        __syncthreads();
        uint4 av = *(const uint4*)(src_bf + (size_t)(i0 + srow) * DIM + kk + sseg);
        uint4 bv = *(const uint4*)(tgt_bf + (size_t)(j0 + srow) * DIM + kk + sseg);
        *(uint4*)&As[srow][sseg] = av;
        *(uint4*)&Bs[srow][sseg] = bv;
        __syncthreads();

        bf16x8 af[2], bf[2];
        af[0] = *(const bf16x8*)&As[wm + fr][fk];
        af[1] = *(const bf16x8*)&As[wm + 16 + fr][fk];
        bf[0] = *(const bf16x8*)&Bs[wn + fr][fk];
        bf[1] = *(const bf16x8*)&Bs[wn + 16 + fr][fk];

        #pragma unroll
        for (int tm = 0; tm < 2; tm++)
            #pragma unroll
            for (int tn = 0; tn < 2; tn++)
                acc[tm][tn] = __builtin_amdgcn_mfma_f32_16x16x32_bf16(
                    af[tm], bf[tn], acc[tm][tn], 0, 0, 0);
    }

    // epilogue: dist -> masked row max/min -> 16-lane reduce -> atomics
    const float INF = __int_as_float(POS_INF_BITS);
    #pragma unroll
    for (int tm = 0; tm < 2; tm++) {
        #pragma unroll
        for (int r = 0; r < 4; r++) {
            const int rl = wm + tm * 16 + quad * 4 + r;  // local row
            float apv = 0.0f;   // neutral for max (all dist >= 0, global init 0)
            float anv = INF;
            #pragma unroll
            for (int tn = 0; tn < 2; tn++) {
                const int cl = wn + tn * 16 + fr;        // local col
                float d = e1s[rl] + e2s[cl] - 2.0f * acc[tm][tn][r];
                d = fmaxf(d, 0.0f);
                if (li[rl] == lj[cl]) apv = fmaxf(apv, d);
                else                  anv = fminf(anv, d);
            }
            #pragma unroll
            for (int off = 1; off < 16; off <<= 1) {
                apv = fmaxf(apv, __shfl_xor(apv, off));
                anv = fminf(anv, __shfl_xor(anv, off));
            }
            if (fr == 0) {
                // non-negative floats: int compare == float compare
                atomicMax((int*)&ap[i0 + rl], __float_as_int(apv));
                atomicMin((int*)&an[i0 + rl], __float_as_int(anv));
            }
        }
    }
}

__global__ __launch_bounds__(256) void loss_kernel(
    const float* __restrict__ ap, const float* __restrict__ an,
    float* __restrict__ out)
{
    const int t = threadIdx.x;
    float s = 0.0f;
    for (int i = t; i < N_PTS; i += 256) {
        float v = ap[i] - an[i] + MARGIN_F;
        s += fmaxf(v, 0.0f);
    }
    for (int off = 32; off; off >>= 1) s += __shfl_down(s, off);
    __shared__ float red[4];
    if ((t & 63) == 0) red[t >> 6] = s;
    __syncthreads();
    if (t == 0) out[0] = (red[0] + red[1] + red[2] + red[3]) / (float)N_PTS;
}

extern "C" void kernel_launch(void* const* d_in, const int* in_sizes, int n_in,
                              void* d_out, int out_size, void* d_ws, size_t ws_size,
                              hipStream_t stream) {
    const float* src   = (const float*)d_in[0];
    const float* tgt   = (const float*)d_in[1];
    const int* labels  = (const int*)d_in[2];

    char* ws = (char*)d_ws;
    const size_t featB = (size_t)N_PTS * DIM * sizeof(unsigned short);  // 4 MiB
    unsigned short* src_bf = (unsigned short*)ws;
    unsigned short* tgt_bf = (unsigned short*)(ws + featB);
    float* e1 = (float*)(ws + 2 * featB);
    float* e2 = e1 + N_PTS;
    float* ap = e2 + N_PTS;
    float* an = ap + N_PTS;

    prep_kernel<<<N_PTS, 128, 0, stream>>>(src, tgt, src_bf, tgt_bf, e1, e2, ap, an);
    dim3 grid(N_PTS / BN, N_PTS / BM);
    dist_kernel<<<grid, 256, 0, stream>>>(src_bf, tgt_bf, e1, e2, labels, ap, an);
    loss_kernel<<<1, 256, 0, stream>>>(ap, an, (float*)d_out);
}

// Round 2
// 109.196 us; speedup vs baseline: 1.2420x; 1.2420x over previous
//
#include <hip/hip_runtime.h>
#include <hip/hip_bf16.h>
#include <stdint.h>

#define N_PTS 4096
#define DIM 512
#define MARGIN_F 0.3f
#define POS_INF_BITS 0x7f800000

typedef short bf16x8 __attribute__((ext_vector_type(8)));
typedef float f32x4 __attribute__((ext_vector_type(4)));

__device__ __forceinline__ unsigned short f2bf(float f) {
    unsigned int b = __float_as_uint(f);
    b += 0x7FFF + ((b >> 16) & 1);   // round-to-nearest-even
    return (unsigned short)(b >> 16);
}

// async global->LDS, 16B per lane; lds ptr must be wave-uniform base (+lane*16 implied)
__device__ __forceinline__ void async16(const unsigned short* g, unsigned short* l) {
    __builtin_amdgcn_global_load_lds(
        (const __attribute__((address_space(1))) unsigned int*)g,
        (__attribute__((address_space(3))) unsigned int*)l,
        16, 0, 0);
}

// One wave per row: bf16 copy + exact fp32 norms + init ap/an. No barriers.
__global__ __launch_bounds__(256) void prep_kernel(
    const float* __restrict__ src, const float* __restrict__ tgt,
    unsigned short* __restrict__ src_bf, unsigned short* __restrict__ tgt_bf,
    float* __restrict__ e1, float* __restrict__ e2,
    float* __restrict__ ap, float* __restrict__ an)
{
    const int row  = blockIdx.x * 4 + (threadIdx.x >> 6);
    const int lane = threadIdx.x & 63;

    const float4* s4 = (const float4*)(src + (size_t)row * DIM);
    const float4* t4 = (const float4*)(tgt + (size_t)row * DIM);
    float4 a0 = s4[lane], a1 = s4[lane + 64];
    float4 b0 = t4[lane], b1 = t4[lane + 64];

    ushort4 u;
    ushort4* so = (ushort4*)(src_bf + (size_t)row * DIM);
    ushort4* to = (ushort4*)(tgt_bf + (size_t)row * DIM);
    u.x = f2bf(a0.x); u.y = f2bf(a0.y); u.z = f2bf(a0.z); u.w = f2bf(a0.w); so[lane] = u;
    u.x = f2bf(a1.x); u.y = f2bf(a1.y); u.z = f2bf(a1.z); u.w = f2bf(a1.w); so[lane + 64] = u;
    u.x = f2bf(b0.x); u.y = f2bf(b0.y); u.z = f2bf(b0.z); u.w = f2bf(b0.w); to[lane] = u;
    u.x = f2bf(b1.x); u.y = f2bf(b1.y); u.z = f2bf(b1.z); u.w = f2bf(b1.w); to[lane + 64] = u;

    float s1 = a0.x*a0.x + a0.y*a0.y + a0.z*a0.z + a0.w*a0.w
             + a1.x*a1.x + a1.y*a1.y + a1.z*a1.z + a1.w*a1.w;
    float s2 = b0.x*b0.x + b0.y*b0.y + b0.z*b0.z + b0.w*b0.w
             + b1.x*b1.x + b1.y*b1.y + b1.z*b1.z + b1.w*b1.w;
    for (int off = 32; off; off >>= 1) {
        s1 += __shfl_down(s1, off);
        s2 += __shfl_down(s2, off);
    }
    if (lane == 0) {
        e1[row] = s1;
        e2[row] = s2;
        ap[row] = 0.0f;
        an[row] = __int_as_float(POS_INF_BITS);
    }
}

#define BM 128
#define BN 128
#define BK 32

__global__ __launch_bounds__(256) void dist_kernel(
    const unsigned short* __restrict__ src_bf,
    const unsigned short* __restrict__ tgt_bf,
    const float* __restrict__ e1, const float* __restrict__ e2,
    const int* __restrict__ labels,
    float* __restrict__ ap, float* __restrict__ an)
{
    // unpadded row-major [128][32] bf16 (64B rows) — required by global_load_lds
    __shared__ unsigned short As[BM * BK];
    __shared__ unsigned short Bs[BN * BK];
    __shared__ int   li[BM];
    __shared__ int   lj[BN];
    __shared__ float e1s[BM];
    __shared__ float e2s[BN];

    const int i0 = blockIdx.y * BM;
    const int j0 = blockIdx.x * BN;
    const int t = threadIdx.x;
    const int lane = t & 63;
    const int wave = t >> 6;

    if (t < BM)      { li[t] = labels[i0 + t]; e1s[t] = e1[i0 + t]; }
    else             { int u = t - BM; lj[u] = labels[j0 + u]; e2s[u] = e2[j0 + u]; }

    // staging: 512 chunks of 16B per tile; thread t handles chunks t and t+256
    // chunk c -> row c>>2, bf16-col (c&3)*8; lds byte off = c*16 (wave-uniform base + lane*16)
    const unsigned short* gA0 = src_bf + (size_t)(i0 + (t >> 2)) * DIM + (t & 3) * 8;
    const unsigned short* gA1 = src_bf + (size_t)(i0 + 64 + (t >> 2)) * DIM + (t & 3) * 8;
    const unsigned short* gB0 = tgt_bf + (size_t)(j0 + (t >> 2)) * DIM + (t & 3) * 8;
    const unsigned short* gB1 = tgt_bf + (size_t)(j0 + 64 + (t >> 2)) * DIM + (t & 3) * 8;
    unsigned short* lds0 = &As[0] + wave * 512;          // elements; chunk base wave*64
    unsigned short* lds1 = &As[0] + 2048 + wave * 512;   // chunk base 256 + wave*64
    unsigned short* ldsB0 = &Bs[0] + wave * 512;
    unsigned short* ldsB1 = &Bs[0] + 2048 + wave * 512;

    // wave -> 64x64 subtile: 4x4 of 16x16 MFMA
    const int wm = (wave >> 1) * 64;
    const int wn = (wave & 1) * 64;
    const int fr = lane & 15;
    const int quad = lane >> 4;

    f32x4 acc[4][4];
    #pragma unroll
    for (int a = 0; a < 4; a++)
        #pragma unroll
        for (int b = 0; b < 4; b++)
            acc[a][b] = (f32x4){0.f, 0.f, 0.f, 0.f};

    for (int kk = 0; kk < DIM; kk += BK) {
        __syncthreads();
        async16(gA0 + kk, lds0);
        async16(gA1 + kk, lds1);
        async16(gB0 + kk, ldsB0);
        async16(gB1 + kk, ldsB1);
        __syncthreads();   // compiler inserts s_waitcnt vmcnt(0) before barrier

        bf16x8 af[4], bf[4];
        #pragma unroll
        for (int x = 0; x < 4; x++) {
            af[x] = *(const bf16x8*)&As[(wm + x * 16 + fr) * BK + quad * 8];
            bf[x] = *(const bf16x8*)&Bs[(wn + x * 16 + fr) * BK + quad * 8];
        }
        #pragma unroll
        for (int tm = 0; tm < 4; tm++)
            #pragma unroll
            for (int tn = 0; tn < 4; tn++)
                acc[tm][tn] = __builtin_amdgcn_mfma_f32_16x16x32_bf16(
                    af[tm], bf[tn], acc[tm][tn], 0, 0, 0);
    }

    // epilogue: dist -> masked row max/min -> 16-lane reduce -> atomics
    const float INF = __int_as_float(POS_INF_BITS);
    #pragma unroll
    for (int tm = 0; tm < 4; tm++) {
        #pragma unroll
        for (int r = 0; r < 4; r++) {
            const int rl = wm + tm * 16 + quad * 4 + r;  // local row
            const float e1v = e1s[rl];
            const int   liv = li[rl];
            float apv = 0.0f;   // neutral for max (dist >= 0, global init 0)
            float anv = INF;
            #pragma unroll
            for (int tn = 0; tn < 4; tn++) {
                const int cl = wn + tn * 16 + fr;        // local col
                float d = e1v + e2s[cl] - 2.0f * acc[tm][tn][r];
                d = fmaxf(d, 0.0f);
                if (liv == lj[cl]) apv = fmaxf(apv, d);
                else               anv = fminf(anv, d);
            }
            #pragma unroll
            for (int off = 1; off < 16; off <<= 1) {
                apv = fmaxf(apv, __shfl_xor(apv, off));
                anv = fminf(anv, __shfl_xor(anv, off));
            }
            if (fr == 0) {
                // non-negative floats: int compare == float compare
                atomicMax((int*)&ap[i0 + rl], __float_as_int(apv));
                atomicMin((int*)&an[i0 + rl], __float_as_int(anv));
            }
        }
    }
}

__global__ __launch_bounds__(256) void loss_kernel(
    const float* __restrict__ ap, const float* __restrict__ an,
    float* __restrict__ out)
{
    const int t = threadIdx.x;
    float s = 0.0f;
    for (int i = t; i < N_PTS; i += 256) {
        float v = ap[i] - an[i] + MARGIN_F;
        s += fmaxf(v, 0.0f);
    }
    for (int off = 32; off; off >>= 1) s += __shfl_down(s, off);
    __shared__ float red[4];
    if ((t & 63) == 0) red[t >> 6] = s;
    __syncthreads();
    if (t == 0) out[0] = (red[0] + red[1] + red[2] + red[3]) / (float)N_PTS;
}

extern "C" void kernel_launch(void* const* d_in, const int* in_sizes, int n_in,
                              void* d_out, int out_size, void* d_ws, size_t ws_size,
                              hipStream_t stream) {
    const float* src   = (const float*)d_in[0];
    const float* tgt   = (const float*)d_in[1];
    const int* labels  = (const int*)d_in[2];

    char* ws = (char*)d_ws;
    const size_t featB = (size_t)N_PTS * DIM * sizeof(unsigned short);  // 4 MiB
    unsigned short* src_bf = (unsigned short*)ws;
    unsigned short* tgt_bf = (unsigned short*)(ws + featB);
    float* e1 = (float*)(ws + 2 * featB);
    float* e2 = e1 + N_PTS;
    float* ap = e2 + N_PTS;
    float* an = ap + N_PTS;

    prep_kernel<<<N_PTS / 4, 256, 0, stream>>>(src, tgt, src_bf, tgt_bf, e1, e2, ap, an);
    dim3 grid(N_PTS / BN, N_PTS / BM);
    dist_kernel<<<grid, 256, 0, stream>>>(src_bf, tgt_bf, e1, e2, labels, ap, an);
    loss_kernel<<<1, 256, 0, stream>>>(ap, an, (float*)d_out);
}